// Round 1
// baseline (76452.319 us; speedup 1.0000x reference)
//
#include <hip/hip_runtime.h>

#define N_NODES 50000
#define N_EDGES 600000
#define N_GRAPHS 64

// constants
#define INV_LIN_IN  0.35355339059327373f   // 1/sqrt(8)
#define INV_LIN_OUT 0.25f                  // 1/sqrt(16)
#define C_INV_S3    0.5773502691896258f    // 1/sqrt(3)
#define C_INV_S2    0.7071067811865476f    // 1/sqrt(2)
#define C_NORM_S    0.04419417382415922f   // 1/sqrt(512)
#define C_NORM_V    0.036084391824351615f  // 1/sqrt(768)

// -------------------- input projection: x[N,32] -> feat[N][16] float4(s,vx,vy,vz)
__global__ void proj_kernel(const float* __restrict__ x,
                            const float* __restrict__ w_in0,
                            const float* __restrict__ w_in1,
                            float4* __restrict__ out) {
    int n = blockIdx.x * blockDim.x + threadIdx.x;
    if (n >= N_NODES) return;
    const float* xp = x + (size_t)n * 32;
    float xs[8], xvx[8], xvy[8], xvz[8];
#pragma unroll
    for (int u = 0; u < 8; ++u) xs[u] = xp[u];
#pragma unroll
    for (int u = 0; u < 8; ++u) {
        xvx[u] = xp[8 + 3 * u + 0];
        xvy[u] = xp[8 + 3 * u + 1];
        xvz[u] = xp[8 + 3 * u + 2];
    }
#pragma unroll
    for (int w = 0; w < 16; ++w) {
        float s = 0.f, vx = 0.f, vy = 0.f, vz = 0.f;
#pragma unroll
        for (int u = 0; u < 8; ++u) {
            float a0 = w_in0[u * 16 + w];   // uniform -> s_load
            float a1 = w_in1[u * 16 + w];
            s  += xs[u]  * a0;
            vx += xvx[u] * a1;
            vy += xvy[u] * a1;
            vz += xvz[u] * a1;
        }
        out[(size_t)n * 16 + w] =
            make_float4(s * INV_LIN_IN, vx * INV_LIN_IN, vy * INV_LIN_IN, vz * INV_LIN_IN);
    }
}

// -------------------- edge tensor product + scatter-add
// feat layout: [N][16] float4 = (s, vx, vy, vz) per channel u
// W: one layer's weights, [5][16][16][16] = W[p][u][v][w]
__global__ __launch_bounds__(256)
void edge_tp_kernel(const float4* __restrict__ feat,
                    float* __restrict__ out,          // [N][16][4] floats
                    const int* __restrict__ row,
                    const int* __restrict__ col,
                    const float* __restrict__ W) {
    int e = blockIdx.x * 256 + threadIdx.x;
    if (e >= N_EDGES) return;
    int r = row[e], c = col[e];
    const float4* af = feat + (size_t)r * 16;
    const float4* bf = feat + (size_t)c * 16;

    float4 b[16];
#pragma unroll
    for (int v = 0; v < 16; ++v) b[v] = bf[v];

    float4 acc[16];
#pragma unroll
    for (int w = 0; w < 16; ++w) acc[w] = make_float4(0.f, 0.f, 0.f, 0.f);

    for (int u = 0; u < 16; ++u) {
        float4 a = af[u];   // (s1, v1x, v1y, v1z)
        const float* w0 = W + u * 256;            // W[0][u][*][*]
        const float* w1 = W + 4096  + u * 256;
        const float* w2 = W + 8192  + u * 256;
        const float* w3 = W + 12288 + u * 256;
        const float* w4 = W + 16384 + u * 256;
#pragma unroll
        for (int v = 0; v < 16; ++v) {
            float4 bv = b[v];   // (s2, v2x, v2y, v2z)
            float ss  = a.x * bv.x;
            float dd  = (a.y * bv.y + a.z * bv.z + a.w * bv.w) * C_INV_S3;
            float svx = a.x * bv.y, svy = a.x * bv.z, svz = a.x * bv.w;
            float vsx = a.y * bv.x, vsy = a.z * bv.x, vsz = a.w * bv.x;
            float cx  = (a.z * bv.w - a.w * bv.z) * C_INV_S2;
            float cy  = (a.w * bv.y - a.y * bv.w) * C_INV_S2;
            float cz  = (a.y * bv.z - a.z * bv.y) * C_INV_S2;
            const float* p0 = w0 + v * 16;
            const float* p1 = w1 + v * 16;
            const float* p2 = w2 + v * 16;
            const float* p3 = w3 + v * 16;
            const float* p4 = w4 + v * 16;
#pragma unroll
            for (int w = 0; w < 16; ++w) {
                float W0v = p0[w], W1v = p1[w], W2v = p2[w], W3v = p3[w], W4v = p4[w];
                acc[w].x += ss  * W0v + dd  * W3v;
                acc[w].y += svx * W1v + vsx * W2v + cx * W4v;
                acc[w].z += svy * W1v + vsy * W2v + cy * W4v;
                acc[w].w += svz * W1v + vsz * W2v + cz * W4v;
            }
        }
    }

    float* op = out + (size_t)r * 64;
#pragma unroll
    for (int w = 0; w < 16; ++w) {
        atomicAdd(op + w * 4 + 0, acc[w].x * C_NORM_S);
        atomicAdd(op + w * 4 + 1, acc[w].y * C_NORM_V);
        atomicAdd(op + w * 4 + 2, acc[w].z * C_NORM_V);
        atomicAdd(op + w * 4 + 3, acc[w].w * C_NORM_V);
    }
}

// -------------------- gate: s' = silu(s), v' = v * sigmoid(s)
__global__ void gate_kernel(float4* __restrict__ feat) {
    int i = blockIdx.x * blockDim.x + threadIdx.x;   // (n*16 + w)
    if (i >= N_NODES * 16) return;
    float4 f = feat[i];
    float g = 1.f / (1.f + __expf(-f.x));
    feat[i] = make_float4(f.x * g, f.y * g, f.z * g, f.w * g);
}

// -------------------- readout: node_out = (s . w_out)*0.25, segment-sum by batch_idx
__global__ void readout_kernel(const float4* __restrict__ feat,
                               const int* __restrict__ batch_idx,
                               const float* __restrict__ w_out,
                               float* __restrict__ energy) {
    __shared__ float bins[N_GRAPHS];
    int t = threadIdx.x;
    if (t < N_GRAPHS) bins[t] = 0.f;
    __syncthreads();
    int n = blockIdx.x * blockDim.x + t;
    if (n < N_NODES) {
        const float4* f = feat + (size_t)n * 16;
        float acc = 0.f;
#pragma unroll
        for (int w = 0; w < 16; ++w) acc += f[w].x * w_out[w];   // w_out uniform -> s_load
        atomicAdd(&bins[batch_idx[n]], acc * INV_LIN_OUT);
    }
    __syncthreads();
    if (t < N_GRAPHS) atomicAdd(&energy[t], bins[t]);
}

extern "C" void kernel_launch(void* const* d_in, const int* in_sizes, int n_in,
                              void* d_out, int out_size, void* d_ws, size_t ws_size,
                              hipStream_t stream) {
    const float* x         = (const float*)d_in[0];
    const int*   row       = (const int*)d_in[1];
    const int*   col       = (const int*)d_in[2];
    const int*   batch_idx = (const int*)d_in[3];
    const float* w_in0     = (const float*)d_in[4];
    const float* w_in1     = (const float*)d_in[5];
    const float* tp_w      = (const float*)d_in[6];   // [3][5][16][16][16]
    const float* w_out0    = (const float*)d_in[7];
    float* energy = (float*)d_out;

    float* bufA = (float*)d_ws;                        // [N][64] floats
    float* bufB = bufA + (size_t)N_NODES * 64;         // [N][64] floats

    proj_kernel<<<(N_NODES + 255) / 256, 256, 0, stream>>>(x, w_in0, w_in1, (float4*)bufA);

    float* fin = bufA;
    float* fout = bufB;
    for (int l = 0; l < 3; ++l) {
        hipMemsetAsync(fout, 0, (size_t)N_NODES * 64 * sizeof(float), stream);
        edge_tp_kernel<<<(N_EDGES + 255) / 256, 256, 0, stream>>>(
            (const float4*)fin, fout, row, col, tp_w + (size_t)l * 20480);
        gate_kernel<<<(N_NODES * 16 + 255) / 256, 256, 0, stream>>>((float4*)fout);
        float* t = fin; fin = fout; fout = t;
    }

    hipMemsetAsync(energy, 0, N_GRAPHS * sizeof(float), stream);
    readout_kernel<<<(N_NODES + 255) / 256, 256, 0, stream>>>(
        (const float4*)fin, batch_idx, w_out0, energy);
}

// Round 2
// 7889.174 us; speedup vs baseline: 9.6908x; 9.6908x over previous
//
#include <hip/hip_runtime.h>

#define N_NODES 50000
#define N_EDGES 600000
#define N_GRAPHS 64
#define BLK_EDGES 64   // edges per block; 256 threads = 64 edges x 4 w-groups

// constants
#define INV_LIN_IN  0.35355339059327373f   // 1/sqrt(8)
#define INV_LIN_OUT 0.25f                  // 1/sqrt(16)
#define C_INV_S3    0.5773502691896258f    // 1/sqrt(3)
#define C_INV_S2    0.7071067811865476f    // 1/sqrt(2)
#define C_NORM_S    0.04419417382415922f   // 1/sqrt(512)
#define C_NORM_V    0.036084391824351615f  // 1/sqrt(768)

// -------------------- input projection: x[N,32] -> feat[N][16] float4(s,vx,vy,vz)
__global__ void proj_kernel(const float* __restrict__ x,
                            const float* __restrict__ w_in0,
                            const float* __restrict__ w_in1,
                            float4* __restrict__ out) {
    int n = blockIdx.x * blockDim.x + threadIdx.x;
    if (n >= N_NODES) return;
    const float* xp = x + (size_t)n * 32;
    float xs[8], xvx[8], xvy[8], xvz[8];
#pragma unroll
    for (int u = 0; u < 8; ++u) xs[u] = xp[u];
#pragma unroll
    for (int u = 0; u < 8; ++u) {
        xvx[u] = xp[8 + 3 * u + 0];
        xvy[u] = xp[8 + 3 * u + 1];
        xvz[u] = xp[8 + 3 * u + 2];
    }
#pragma unroll
    for (int w = 0; w < 16; ++w) {
        float s = 0.f, vx = 0.f, vy = 0.f, vz = 0.f;
#pragma unroll
        for (int u = 0; u < 8; ++u) {
            float a0 = w_in0[u * 16 + w];   // wave-uniform -> s_load
            float a1 = w_in1[u * 16 + w];
            s  += xs[u]  * a0;
            vx += xvx[u] * a1;
            vy += xvy[u] * a1;
            vz += xvz[u] * a1;
        }
        out[(size_t)n * 16 + w] =
            make_float4(s * INV_LIN_IN, vx * INV_LIN_IN, vy * INV_LIN_IN, vz * INV_LIN_IN);
    }
}

// -------------------- edge tensor product + scatter-add
// feat layout: [N][16] float4 = (s, vx, vy, vz) per channel u
// W: one layer's weights, [5][16][16][16] = W[p][u][v][w]
// 4 threads per edge; thread handles w in [wb, wb+4). acc = 4 float4 -> 16 VGPR.
__global__ __launch_bounds__(256, 4)
void edge_tp_kernel(const float4* __restrict__ feat,
                    float* __restrict__ out,          // [N][16][4] floats
                    const int* __restrict__ row,
                    const int* __restrict__ col,
                    const float* __restrict__ W) {
    __shared__ float4 sA[BLK_EDGES][17];   // +1 float4 pad: 68-dword row stride -> 2-way bank alias (free)
    __shared__ float4 sB[BLK_EDGES][17];
    __shared__ int sR[BLK_EDGES];
    __shared__ int sC[BLK_EDGES];

    const int t = threadIdx.x;
    const int base = blockIdx.x * BLK_EDGES;

    if (t < BLK_EDGES) sR[t] = row[base + t];
    else if (t < 2 * BLK_EDGES) sC[t - BLK_EDGES] = col[base + t - BLK_EDGES];
    __syncthreads();

    // gather: 64 edges x 16 float4 each for A and B; consecutive threads read
    // consecutive u within an edge -> 256B contiguous segments
#pragma unroll
    for (int idx = t; idx < BLK_EDGES * 16; idx += 256) {
        int e = idx >> 4, u = idx & 15;
        sA[e][u] = feat[(size_t)sR[e] * 16 + u];
        sB[e][u] = feat[(size_t)sC[e] * 16 + u];
    }
    __syncthreads();

    const int el = t >> 2;            // local edge 0..63
    const int wb = (t & 3) * 4;       // w-group base: 0,4,8,12
    const float* Wt = W + wb;         // lane-dependent but 64B-coalesced across the quad

    float4 acc0 = make_float4(0.f, 0.f, 0.f, 0.f);
    float4 acc1 = make_float4(0.f, 0.f, 0.f, 0.f);
    float4 acc2 = make_float4(0.f, 0.f, 0.f, 0.f);
    float4 acc3 = make_float4(0.f, 0.f, 0.f, 0.f);

    for (int u = 0; u < 16; ++u) {
        float4 a = sA[el][u];
        const float* Wu = Wt + u * 256;
#pragma unroll 4
        for (int v = 0; v < 16; ++v) {
            float4 b = sB[el][v];
            // per-(u,v) path activations
            float ss  = a.x * b.x;
            float dd  = (a.y * b.y + a.z * b.z + a.w * b.w) * C_INV_S3;
            float svx = a.x * b.y, svy = a.x * b.z, svz = a.x * b.w;
            float vsx = a.y * b.x, vsy = a.z * b.x, vsz = a.w * b.x;
            float cx  = (a.z * b.w - a.w * b.z) * C_INV_S2;
            float cy  = (a.w * b.y - a.y * b.w) * C_INV_S2;
            float cz  = (a.y * b.z - a.z * b.y) * C_INV_S2;
            // weights for this thread's 4 w-outputs (float4-aligned: wb multiple of 4)
            const float4 w0 = *(const float4*)(Wu + v * 16);
            const float4 w1 = *(const float4*)(Wu + 4096  + v * 16);
            const float4 w2 = *(const float4*)(Wu + 8192  + v * 16);
            const float4 w3 = *(const float4*)(Wu + 12288 + v * 16);
            const float4 w4 = *(const float4*)(Wu + 16384 + v * 16);

            acc0.x += ss * w0.x + dd * w3.x;
            acc0.y += svx * w1.x + vsx * w2.x + cx * w4.x;
            acc0.z += svy * w1.x + vsy * w2.x + cy * w4.x;
            acc0.w += svz * w1.x + vsz * w2.x + cz * w4.x;

            acc1.x += ss * w0.y + dd * w3.y;
            acc1.y += svx * w1.y + vsx * w2.y + cx * w4.y;
            acc1.z += svy * w1.y + vsy * w2.y + cy * w4.y;
            acc1.w += svz * w1.y + vsz * w2.y + cz * w4.y;

            acc2.x += ss * w0.z + dd * w3.z;
            acc2.y += svx * w1.z + vsx * w2.z + cx * w4.z;
            acc2.z += svy * w1.z + vsy * w2.z + cy * w4.z;
            acc2.w += svz * w1.z + vsz * w2.z + cz * w4.z;

            acc3.x += ss * w0.w + dd * w3.w;
            acc3.y += svx * w1.w + vsx * w2.w + cx * w4.w;
            acc3.z += svy * w1.w + vsy * w2.w + cy * w4.w;
            acc3.w += svz * w1.w + vsz * w2.w + cz * w4.w;
        }
    }

    // scatter: out[r*64 + w*4 + comp], w = wb + j
    float* op = out + (size_t)sR[el] * 64 + wb * 4;
    atomicAdd(op + 0,  acc0.x * C_NORM_S);
    atomicAdd(op + 1,  acc0.y * C_NORM_V);
    atomicAdd(op + 2,  acc0.z * C_NORM_V);
    atomicAdd(op + 3,  acc0.w * C_NORM_V);
    atomicAdd(op + 4,  acc1.x * C_NORM_S);
    atomicAdd(op + 5,  acc1.y * C_NORM_V);
    atomicAdd(op + 6,  acc1.z * C_NORM_V);
    atomicAdd(op + 7,  acc1.w * C_NORM_V);
    atomicAdd(op + 8,  acc2.x * C_NORM_S);
    atomicAdd(op + 9,  acc2.y * C_NORM_V);
    atomicAdd(op + 10, acc2.z * C_NORM_V);
    atomicAdd(op + 11, acc2.w * C_NORM_V);
    atomicAdd(op + 12, acc3.x * C_NORM_S);
    atomicAdd(op + 13, acc3.y * C_NORM_V);
    atomicAdd(op + 14, acc3.z * C_NORM_V);
    atomicAdd(op + 15, acc3.w * C_NORM_V);
}

// -------------------- gate: s' = silu(s), v' = v * sigmoid(s)
__global__ void gate_kernel(float4* __restrict__ feat) {
    int i = blockIdx.x * blockDim.x + threadIdx.x;   // (n*16 + w)
    if (i >= N_NODES * 16) return;
    float4 f = feat[i];
    float g = 1.f / (1.f + __expf(-f.x));
    feat[i] = make_float4(f.x * g, f.y * g, f.z * g, f.w * g);
}

// -------------------- readout: node_out = (s . w_out)*0.25, segment-sum by batch_idx
__global__ void readout_kernel(const float4* __restrict__ feat,
                               const int* __restrict__ batch_idx,
                               const float* __restrict__ w_out,
                               float* __restrict__ energy) {
    __shared__ float bins[N_GRAPHS];
    int t = threadIdx.x;
    if (t < N_GRAPHS) bins[t] = 0.f;
    __syncthreads();
    int n = blockIdx.x * blockDim.x + t;
    if (n < N_NODES) {
        const float4* f = feat + (size_t)n * 16;
        float acc = 0.f;
#pragma unroll
        for (int w = 0; w < 16; ++w) acc += f[w].x * w_out[w];
        atomicAdd(&bins[batch_idx[n]], acc * INV_LIN_OUT);
    }
    __syncthreads();
    if (t < N_GRAPHS) atomicAdd(&energy[t], bins[t]);
}

extern "C" void kernel_launch(void* const* d_in, const int* in_sizes, int n_in,
                              void* d_out, int out_size, void* d_ws, size_t ws_size,
                              hipStream_t stream) {
    const float* x         = (const float*)d_in[0];
    const int*   row       = (const int*)d_in[1];
    const int*   col       = (const int*)d_in[2];
    const int*   batch_idx = (const int*)d_in[3];
    const float* w_in0     = (const float*)d_in[4];
    const float* w_in1     = (const float*)d_in[5];
    const float* tp_w      = (const float*)d_in[6];   // [3][5][16][16][16]
    const float* w_out0    = (const float*)d_in[7];
    float* energy = (float*)d_out;

    float* bufA = (float*)d_ws;                        // [N][64] floats
    float* bufB = bufA + (size_t)N_NODES * 64;         // [N][64] floats

    proj_kernel<<<(N_NODES + 255) / 256, 256, 0, stream>>>(x, w_in0, w_in1, (float4*)bufA);

    float* fin = bufA;
    float* fout = bufB;
    for (int l = 0; l < 3; ++l) {
        hipMemsetAsync(fout, 0, (size_t)N_NODES * 64 * sizeof(float), stream);
        edge_tp_kernel<<<N_EDGES / BLK_EDGES, 256, 0, stream>>>(
            (const float4*)fin, fout, row, col, tp_w + (size_t)l * 20480);
        gate_kernel<<<(N_NODES * 16 + 255) / 256, 256, 0, stream>>>((float4*)fout);
        float* t = fin; fin = fout; fout = t;
    }

    hipMemsetAsync(energy, 0, N_GRAPHS * sizeof(float), stream);
    readout_kernel<<<(N_NODES + 255) / 256, 256, 0, stream>>>(
        (const float4*)fin, batch_idx, w_out0, energy);
}

// Round 3
// 1757.890 us; speedup vs baseline: 43.4910x; 4.4879x over previous
//
#include <hip/hip_runtime.h>
#include <hip/hip_bf16.h>

#define N_NODES 50000
#define N_EDGES 600000
#define N_GRAPHS 64
#define BLK_EDGES 64   // edges per block; 4 waves x 16-edge MFMA tiles

// constants
#define INV_LIN_IN  0.35355339059327373f   // 1/sqrt(8)
#define INV_LIN_OUT 0.25f                  // 1/sqrt(16)
#define C_INV_S3    0.5773502691896258f    // 1/sqrt(3)
#define C_INV_S2    0.7071067811865476f    // 1/sqrt(2)
#define C_NORM_S    0.04419417382415922f   // 1/sqrt(512)
#define C_NORM_V    0.036084391824351615f  // 1/sqrt(768)

typedef __attribute__((ext_vector_type(8))) short short8;
typedef __attribute__((ext_vector_type(4))) float f32x4;

// -------------------- input projection: x[N,32] -> feat[N][16] float4(s,vx,vy,vz)
__global__ void proj_kernel(const float* __restrict__ x,
                            const float* __restrict__ w_in0,
                            const float* __restrict__ w_in1,
                            float4* __restrict__ out) {
    int n = blockIdx.x * blockDim.x + threadIdx.x;
    if (n >= N_NODES) return;
    const float* xp = x + (size_t)n * 32;
    float xs[8], xvx[8], xvy[8], xvz[8];
#pragma unroll
    for (int u = 0; u < 8; ++u) xs[u] = xp[u];
#pragma unroll
    for (int u = 0; u < 8; ++u) {
        xvx[u] = xp[8 + 3 * u + 0];
        xvy[u] = xp[8 + 3 * u + 1];
        xvz[u] = xp[8 + 3 * u + 2];
    }
#pragma unroll
    for (int w = 0; w < 16; ++w) {
        float s = 0.f, vx = 0.f, vy = 0.f, vz = 0.f;
#pragma unroll
        for (int u = 0; u < 8; ++u) {
            float a0 = w_in0[u * 16 + w];
            float a1 = w_in1[u * 16 + w];
            s  += xs[u]  * a0;
            vx += xvx[u] * a1;
            vy += xvy[u] * a1;
            vz += xvz[u] * a1;
        }
        out[(size_t)n * 16 + w] =
            make_float4(s * INV_LIN_IN, vx * INV_LIN_IN, vy * INV_LIN_IN, vz * INV_LIN_IN);
    }
}

// -------------------- weight pre-swizzle: fp32 [3][5][16(u)][16(v)][16(w)]
// -> bf16 in MFMA B-fragment order, norm constants folded.
// flat index i = (((l*5 + p)*8 + c)*64 + lane)*8 + j
// element = W[l][p][u][v][n] * scale(p), kk = c*32 + (lane>>4)*8 + j, u=kk>>4, v=kk&15, n=lane&15
__global__ void swizzle_w_kernel(const float* __restrict__ tp_w, short* __restrict__ wbf) {
    int i = blockIdx.x * 256 + threadIdx.x;
    if (i >= 3 * 20480) return;
    int j    = i & 7;
    int t1   = i >> 3;
    int lane = t1 & 63;
    int t2   = t1 >> 6;
    int c    = t2 & 7;
    int t3   = t2 >> 3;
    int p    = t3 % 5;
    int l    = t3 / 5;
    int kk = c * 32 + (lane >> 4) * 8 + j;
    int u = kk >> 4, v = kk & 15, n = lane & 15;
    float scale;
    if      (p == 0) scale = C_NORM_S;
    else if (p == 3) scale = C_INV_S3 * C_NORM_S;
    else if (p == 4) scale = C_INV_S2 * C_NORM_V;
    else             scale = C_NORM_V;   // p==1, p==2
    float val = tp_w[(size_t)(l * 5 + p) * 4096 + u * 256 + v * 16 + n] * scale;
    __hip_bfloat16 h = __float2bfloat16(val);
    wbf[i] = *reinterpret_cast<short*>(&h);
}

static __device__ inline __hip_bfloat162 cvt2(float x, float y) {
    return __float22bfloat162_rn(make_float2(x, y));
}

// -------------------- edge tensor product via MFMA + atomic scatter
// feat: [N][16] float4(s,vx,vy,vz). wbf: one layer, B-frag order (see swizzle).
// Each wave: 16 edges. K=256 (u,v) in 8 chunks of 32; 11 z-channels -> 11 MFMAs/chunk.
__global__ __launch_bounds__(256, 4)
void edge_tp_kernel(const float4* __restrict__ feat,
                    float* __restrict__ out,          // [N][16][4] floats
                    const int* __restrict__ row,
                    const int* __restrict__ col,
                    const short* __restrict__ wbf) {
    __shared__ float4 sA[BLK_EDGES][17];
    __shared__ float4 sB[BLK_EDGES][17];
    __shared__ int sR[BLK_EDGES];
    __shared__ int sC[BLK_EDGES];

    const int t = threadIdx.x;
    const int base = blockIdx.x * BLK_EDGES;

    if (t < BLK_EDGES) sR[t] = row[base + t];
    else if (t < 2 * BLK_EDGES) sC[t - BLK_EDGES] = col[base + t - BLK_EDGES];
    __syncthreads();

#pragma unroll
    for (int idx = t; idx < BLK_EDGES * 16; idx += 256) {
        int e = idx >> 4, u = idx & 15;
        sA[e][u] = feat[(size_t)sR[e] * 16 + u];
        sB[e][u] = feat[(size_t)sC[e] * 16 + u];
    }
    __syncthreads();

    const int lane = t & 63;
    const int wave = t >> 6;
    const int q = lane >> 4;        // quad index 0..3
    const int m = lane & 15;        // edge-in-tile (A rows) / w column (B,D)
    const int e = wave * 16 + m;    // local edge for A/B fragments
    const int v0 = (q & 1) * 8;

    f32x4 acc_s = {0.f, 0.f, 0.f, 0.f};
    f32x4 acc_x = {0.f, 0.f, 0.f, 0.f};
    f32x4 acc_y = {0.f, 0.f, 0.f, 0.f};
    f32x4 acc_z = {0.f, 0.f, 0.f, 0.f};

    const short8* wf = (const short8*)wbf;   // frag index: (p*8 + c)*64 + lane

#pragma unroll 2
    for (int c = 0; c < 8; ++c) {
        // B-fragments for the 5 weight paths (coalesced 16B/lane, L2-resident)
        short8 w0f = wf[(0 * 8 + c) * 64 + lane];
        short8 w1f = wf[(1 * 8 + c) * 64 + lane];
        short8 w2f = wf[(2 * 8 + c) * 64 + lane];
        short8 w3f = wf[(3 * 8 + c) * 64 + lane];
        short8 w4f = wf[(4 * 8 + c) * 64 + lane];

        const int u = 2 * c + (q >> 1);
        float4 A = sA[e][u];
        float4 Bv[8];
#pragma unroll
        for (int k = 0; k < 8; ++k) Bv[k] = sB[e][v0 + k];

        union { short8 v; __hip_bfloat162 h[4]; } z;

        // ss -> W0 (acc_s)
#pragma unroll
        for (int k = 0; k < 4; ++k)
            z.h[k] = cvt2(A.x * Bv[2*k].x, A.x * Bv[2*k+1].x);
        acc_s = __builtin_amdgcn_mfma_f32_16x16x32_bf16(z.v, w0f, acc_s, 0, 0, 0);

        // dot(v1,v2) -> W3 (acc_s)
#pragma unroll
        for (int k = 0; k < 4; ++k)
            z.h[k] = cvt2(A.y * Bv[2*k].y   + A.z * Bv[2*k].z   + A.w * Bv[2*k].w,
                          A.y * Bv[2*k+1].y + A.z * Bv[2*k+1].z + A.w * Bv[2*k+1].w);
        acc_s = __builtin_amdgcn_mfma_f32_16x16x32_bf16(z.v, w3f, acc_s, 0, 0, 0);

        // s1*v2x -> W1 (acc_x)
#pragma unroll
        for (int k = 0; k < 4; ++k)
            z.h[k] = cvt2(A.x * Bv[2*k].y, A.x * Bv[2*k+1].y);
        acc_x = __builtin_amdgcn_mfma_f32_16x16x32_bf16(z.v, w1f, acc_x, 0, 0, 0);
        // v1x*s2 -> W2 (acc_x)
#pragma unroll
        for (int k = 0; k < 4; ++k)
            z.h[k] = cvt2(A.y * Bv[2*k].x, A.y * Bv[2*k+1].x);
        acc_x = __builtin_amdgcn_mfma_f32_16x16x32_bf16(z.v, w2f, acc_x, 0, 0, 0);
        // cross_x = v1y*v2z - v1z*v2y -> W4 (acc_x)
#pragma unroll
        for (int k = 0; k < 4; ++k)
            z.h[k] = cvt2(A.z * Bv[2*k].w   - A.w * Bv[2*k].z,
                          A.z * Bv[2*k+1].w - A.w * Bv[2*k+1].z);
        acc_x = __builtin_amdgcn_mfma_f32_16x16x32_bf16(z.v, w4f, acc_x, 0, 0, 0);

        // s1*v2y -> W1 (acc_y)
#pragma unroll
        for (int k = 0; k < 4; ++k)
            z.h[k] = cvt2(A.x * Bv[2*k].z, A.x * Bv[2*k+1].z);
        acc_y = __builtin_amdgcn_mfma_f32_16x16x32_bf16(z.v, w1f, acc_y, 0, 0, 0);
        // v1y*s2 -> W2 (acc_y)
#pragma unroll
        for (int k = 0; k < 4; ++k)
            z.h[k] = cvt2(A.z * Bv[2*k].x, A.z * Bv[2*k+1].x);
        acc_y = __builtin_amdgcn_mfma_f32_16x16x32_bf16(z.v, w2f, acc_y, 0, 0, 0);
        // cross_y = v1z*v2x - v1x*v2z -> W4 (acc_y)
#pragma unroll
        for (int k = 0; k < 4; ++k)
            z.h[k] = cvt2(A.w * Bv[2*k].y   - A.y * Bv[2*k].w,
                          A.w * Bv[2*k+1].y - A.y * Bv[2*k+1].w);
        acc_y = __builtin_amdgcn_mfma_f32_16x16x32_bf16(z.v, w4f, acc_y, 0, 0, 0);

        // s1*v2z -> W1 (acc_z)
#pragma unroll
        for (int k = 0; k < 4; ++k)
            z.h[k] = cvt2(A.x * Bv[2*k].w, A.x * Bv[2*k+1].w);
        acc_z = __builtin_amdgcn_mfma_f32_16x16x32_bf16(z.v, w1f, acc_z, 0, 0, 0);
        // v1z*s2 -> W2 (acc_z)
#pragma unroll
        for (int k = 0; k < 4; ++k)
            z.h[k] = cvt2(A.w * Bv[2*k].x, A.w * Bv[2*k+1].x);
        acc_z = __builtin_amdgcn_mfma_f32_16x16x32_bf16(z.v, w2f, acc_z, 0, 0, 0);
        // cross_z = v1x*v2y - v1y*v2x -> W4 (acc_z)
#pragma unroll
        for (int k = 0; k < 4; ++k)
            z.h[k] = cvt2(A.y * Bv[2*k].z   - A.z * Bv[2*k].y,
                          A.y * Bv[2*k+1].z - A.z * Bv[2*k+1].y);
        acc_z = __builtin_amdgcn_mfma_f32_16x16x32_bf16(z.v, w4f, acc_z, 0, 0, 0);
    }

    // D layout: row = q*4 + r (edge in tile), col = m (w). Norms folded into W.
    const int w = m;
#pragma unroll
    for (int r = 0; r < 4; ++r) {
        int node = sR[wave * 16 + q * 4 + r];
        float* op = out + (size_t)node * 64 + w * 4;
        atomicAdd(op + 0, acc_s[r]);
        atomicAdd(op + 1, acc_x[r]);
        atomicAdd(op + 2, acc_y[r]);
        atomicAdd(op + 3, acc_z[r]);
    }
}

// -------------------- gate: s' = silu(s), v' = v * sigmoid(s)
__global__ void gate_kernel(float4* __restrict__ feat) {
    int i = blockIdx.x * blockDim.x + threadIdx.x;   // (n*16 + w)
    if (i >= N_NODES * 16) return;
    float4 f = feat[i];
    float g = 1.f / (1.f + __expf(-f.x));
    feat[i] = make_float4(f.x * g, f.y * g, f.z * g, f.w * g);
}

// -------------------- readout
__global__ void readout_kernel(const float4* __restrict__ feat,
                               const int* __restrict__ batch_idx,
                               const float* __restrict__ w_out,
                               float* __restrict__ energy) {
    __shared__ float bins[N_GRAPHS];
    int t = threadIdx.x;
    if (t < N_GRAPHS) bins[t] = 0.f;
    __syncthreads();
    int n = blockIdx.x * blockDim.x + t;
    if (n < N_NODES) {
        const float4* f = feat + (size_t)n * 16;
        float acc = 0.f;
#pragma unroll
        for (int w = 0; w < 16; ++w) acc += f[w].x * w_out[w];
        atomicAdd(&bins[batch_idx[n]], acc * INV_LIN_OUT);
    }
    __syncthreads();
    if (t < N_GRAPHS) atomicAdd(&energy[t], bins[t]);
}

extern "C" void kernel_launch(void* const* d_in, const int* in_sizes, int n_in,
                              void* d_out, int out_size, void* d_ws, size_t ws_size,
                              hipStream_t stream) {
    const float* x         = (const float*)d_in[0];
    const int*   row       = (const int*)d_in[1];
    const int*   col       = (const int*)d_in[2];
    const int*   batch_idx = (const int*)d_in[3];
    const float* w_in0     = (const float*)d_in[4];
    const float* w_in1     = (const float*)d_in[5];
    const float* tp_w      = (const float*)d_in[6];   // [3][5][16][16][16]
    const float* w_out0    = (const float*)d_in[7];
    float* energy = (float*)d_out;

    float* bufA = (float*)d_ws;                        // [N][64] floats
    float* bufB = bufA + (size_t)N_NODES * 64;         // [N][64] floats
    short* wbf  = (short*)(bufB + (size_t)N_NODES * 64);  // [3][5][8][64][8] bf16

    swizzle_w_kernel<<<(3 * 20480 + 255) / 256, 256, 0, stream>>>(tp_w, wbf);
    proj_kernel<<<(N_NODES + 255) / 256, 256, 0, stream>>>(x, w_in0, w_in1, (float4*)bufA);

    float* fin = bufA;
    float* fout = bufB;
    for (int l = 0; l < 3; ++l) {
        hipMemsetAsync(fout, 0, (size_t)N_NODES * 64 * sizeof(float), stream);
        edge_tp_kernel<<<N_EDGES / BLK_EDGES, 256, 0, stream>>>(
            (const float4*)fin, fout, row, col, wbf + (size_t)l * 20480);
        gate_kernel<<<(N_NODES * 16 + 255) / 256, 256, 0, stream>>>((float4*)fout);
        float* t = fin; fin = fout; fout = t;
    }

    hipMemsetAsync(energy, 0, N_GRAPHS * sizeof(float), stream);
    readout_kernel<<<(N_NODES + 255) / 256, 256, 0, stream>>>(
        (const float4*)fin, batch_idx, w_out0, energy);
}

// Round 5
// 1163.789 us; speedup vs baseline: 65.6926x; 1.5105x over previous
//
#include <hip/hip_runtime.h>
#include <hip/hip_bf16.h>

#define N_NODES 50000
#define N_EDGES 600000
#define N_GRAPHS 64
#define BLK_EDGES 64   // edges per block; 4 waves x 16-edge MFMA tiles
#define NPART 196      // ceil(50000/256) scan partials

// constants
#define INV_LIN_IN  0.35355339059327373f   // 1/sqrt(8)
#define INV_LIN_OUT 0.25f                  // 1/sqrt(16)
#define C_INV_S3    0.5773502691896258f    // 1/sqrt(3)
#define C_INV_S2    0.7071067811865476f    // 1/sqrt(2)
#define C_NORM_S    0.04419417382415922f   // 1/sqrt(512)
#define C_NORM_V    0.036084391824351615f  // 1/sqrt(768)

typedef __attribute__((ext_vector_type(8))) short short8;
typedef __attribute__((ext_vector_type(4))) float f32x4;

// ==================== sort edges by destination (row); pack (row,col) in one int ====
__global__ void hist_kernel(const int* __restrict__ row, int* __restrict__ counts) {
    int e = blockIdx.x * 256 + threadIdx.x;
    if (e < N_EDGES) atomicAdd(&counts[row[e]], 1);
}

__global__ void scan_part_kernel(const int* __restrict__ counts, int* __restrict__ partial) {
    __shared__ int sm[256];
    int t = threadIdx.x;
    int i = blockIdx.x * 256 + t;
    sm[t] = (i < N_NODES) ? counts[i] : 0;
    __syncthreads();
    for (int s = 128; s > 0; s >>= 1) {
        if (t < s) sm[t] += sm[t + s];
        __syncthreads();
    }
    if (t == 0) partial[blockIdx.x] = sm[0];
}

__global__ void scan_partials_kernel(const int* __restrict__ partial, int* __restrict__ partOff) {
    __shared__ int sm[256];
    int t = threadIdx.x;
    int v = (t < NPART) ? partial[t] : 0;
    sm[t] = v;
    __syncthreads();
    for (int s = 1; s < 256; s <<= 1) {
        int add = (t >= s) ? sm[t - s] : 0;
        __syncthreads();
        sm[t] += add;
        __syncthreads();
    }
    if (t < NPART) partOff[t] = sm[t] - v;   // exclusive
}

__global__ void scan_final_kernel(const int* __restrict__ counts,
                                  const int* __restrict__ partOff,
                                  int* __restrict__ cursor) {
    __shared__ int sm[256];
    int t = threadIdx.x;
    int i = blockIdx.x * 256 + t;
    int v = (i < N_NODES) ? counts[i] : 0;
    sm[t] = v;
    __syncthreads();
    for (int s = 1; s < 256; s <<= 1) {
        int add = (t >= s) ? sm[t - s] : 0;
        __syncthreads();
        sm[t] += add;
        __syncthreads();
    }
    if (i < N_NODES) cursor[i] = sm[t] - v + partOff[blockIdx.x];   // exclusive offsets
}

__global__ void scatter_kernel(const int* __restrict__ row, const int* __restrict__ col,
                               int* __restrict__ cursor, int* __restrict__ sortedRC) {
    int e = blockIdx.x * 256 + threadIdx.x;
    if (e < N_EDGES) {
        int n = row[e];
        int pos = atomicAdd(&cursor[n], 1);
        sortedRC[pos] = n | (col[e] << 16);   // node ids < 50000 < 65536
    }
}

// -------------------- input projection: x[N,32] -> feat[N][16] float4(s,vx,vy,vz)
__global__ void proj_kernel(const float* __restrict__ x,
                            const float* __restrict__ w_in0,
                            const float* __restrict__ w_in1,
                            float4* __restrict__ out) {
    int n = blockIdx.x * blockDim.x + threadIdx.x;
    if (n >= N_NODES) return;
    const float* xp = x + (size_t)n * 32;
    float xs[8], xvx[8], xvy[8], xvz[8];
#pragma unroll
    for (int u = 0; u < 8; ++u) xs[u] = xp[u];
#pragma unroll
    for (int u = 0; u < 8; ++u) {
        xvx[u] = xp[8 + 3 * u + 0];
        xvy[u] = xp[8 + 3 * u + 1];
        xvz[u] = xp[8 + 3 * u + 2];
    }
#pragma unroll
    for (int w = 0; w < 16; ++w) {
        float s = 0.f, vx = 0.f, vy = 0.f, vz = 0.f;
#pragma unroll
        for (int u = 0; u < 8; ++u) {
            float a0 = w_in0[u * 16 + w];
            float a1 = w_in1[u * 16 + w];
            s  += xs[u]  * a0;
            vx += xvx[u] * a1;
            vy += xvy[u] * a1;
            vz += xvz[u] * a1;
        }
        out[(size_t)n * 16 + w] =
            make_float4(s * INV_LIN_IN, vx * INV_LIN_IN, vy * INV_LIN_IN, vz * INV_LIN_IN);
    }
}

// -------------------- weight pre-swizzle: fp32 [3][5][16(u)][16(v)][16(w)]
// -> bf16 in MFMA B-fragment order, norm constants folded.
__global__ void swizzle_w_kernel(const float* __restrict__ tp_w, short* __restrict__ wbf) {
    int i = blockIdx.x * 256 + threadIdx.x;
    if (i >= 3 * 20480) return;
    int j    = i & 7;
    int t1   = i >> 3;
    int lane = t1 & 63;
    int t2   = t1 >> 6;
    int c    = t2 & 7;
    int t3   = t2 >> 3;
    int p    = t3 % 5;
    int l    = t3 / 5;
    int kk = c * 32 + (lane >> 4) * 8 + j;
    int u = kk >> 4, v = kk & 15, n = lane & 15;
    float scale;
    if      (p == 0) scale = C_NORM_S;
    else if (p == 3) scale = C_INV_S3 * C_NORM_S;
    else if (p == 4) scale = C_INV_S2 * C_NORM_V;
    else             scale = C_NORM_V;   // p==1, p==2
    float val = tp_w[(size_t)(l * 5 + p) * 4096 + u * 256 + v * 16 + n] * scale;
    __hip_bfloat16 h = __float2bfloat16(val);
    wbf[i] = *reinterpret_cast<short*>(&h);
}

static __device__ inline __hip_bfloat162 cvt2(float x, float y) {
    return __float22bfloat162_rn(make_float2(x, y));
}

// -------------------- edge tensor product via MFMA + segmented scatter
// Edges pre-sorted by destination node. Epilogue aggregates per distinct node
// in LDS, then one global atomic set per segment.
__global__ __launch_bounds__(256, 4)
void edge_tp_kernel(const float4* __restrict__ feat,
                    float* __restrict__ out,          // [N][16][4] floats
                    const int* __restrict__ sortedRC,
                    const short* __restrict__ wbf) {
    __shared__ float4 pool[2][BLK_EDGES][17];   // sA/sB during compute; segOut in epilogue
    __shared__ int sR[BLK_EDGES];
    __shared__ int sC[BLK_EDGES];
    __shared__ int sSeg[BLK_EDGES];
    __shared__ int sSegNode[BLK_EDGES];
    __shared__ int sNseg;

    float4 (*sA)[17] = pool[0];
    float4 (*sB)[17] = pool[1];
    float* segOut = (float*)&pool[0][0][0];     // 64 segs x 64 floats = 16 KB

    const int t = threadIdx.x;
    const int base = blockIdx.x * BLK_EDGES;

    if (t < BLK_EDGES) {
        int v = sortedRC[base + t];
        sR[t] = v & 0xFFFF;
        sC[t] = ((unsigned)v) >> 16;
    }
    __syncthreads();

#pragma unroll
    for (int idx = t; idx < BLK_EDGES * 16; idx += 256) {
        int e = idx >> 4, u = idx & 15;
        sA[e][u] = feat[(size_t)sR[e] * 16 + u];   // sorted rows -> L1-resident runs
        sB[e][u] = feat[(size_t)sC[e] * 16 + u];
    }
    __syncthreads();

    const int lane = t & 63;
    const int wave = t >> 6;
    const int q = lane >> 4;        // quad index 0..3
    const int m = lane & 15;        // edge-in-tile (A rows) / w column (B,D)
    const int e = wave * 16 + m;    // local edge for A/B fragments
    const int v0 = (q & 1) * 8;

    f32x4 acc_s = {0.f, 0.f, 0.f, 0.f};
    f32x4 acc_x = {0.f, 0.f, 0.f, 0.f};
    f32x4 acc_y = {0.f, 0.f, 0.f, 0.f};
    f32x4 acc_z = {0.f, 0.f, 0.f, 0.f};

    const short8* wf = (const short8*)wbf;   // frag index: (p*8 + c)*64 + lane

#pragma unroll 2
    for (int c = 0; c < 8; ++c) {
        short8 w0f = wf[(0 * 8 + c) * 64 + lane];
        short8 w1f = wf[(1 * 8 + c) * 64 + lane];
        short8 w2f = wf[(2 * 8 + c) * 64 + lane];
        short8 w3f = wf[(3 * 8 + c) * 64 + lane];
        short8 w4f = wf[(4 * 8 + c) * 64 + lane];

        const int u = 2 * c + (q >> 1);
        float4 A = sA[e][u];
        float4 Bv[8];
#pragma unroll
        for (int k = 0; k < 8; ++k) Bv[k] = sB[e][v0 + k];

        union { short8 v; __hip_bfloat162 h[4]; } z;

        // ss -> W0 (acc_s)
#pragma unroll
        for (int k = 0; k < 4; ++k)
            z.h[k] = cvt2(A.x * Bv[2*k].x, A.x * Bv[2*k+1].x);
        acc_s = __builtin_amdgcn_mfma_f32_16x16x32_bf16(z.v, w0f, acc_s, 0, 0, 0);

        // dot(v1,v2) -> W3 (acc_s)
#pragma unroll
        for (int k = 0; k < 4; ++k)
            z.h[k] = cvt2(A.y * Bv[2*k].y   + A.z * Bv[2*k].z   + A.w * Bv[2*k].w,
                          A.y * Bv[2*k+1].y + A.z * Bv[2*k+1].z + A.w * Bv[2*k+1].w);
        acc_s = __builtin_amdgcn_mfma_f32_16x16x32_bf16(z.v, w3f, acc_s, 0, 0, 0);

        // s1*v2x -> W1 (acc_x)
#pragma unroll
        for (int k = 0; k < 4; ++k)
            z.h[k] = cvt2(A.x * Bv[2*k].y, A.x * Bv[2*k+1].y);
        acc_x = __builtin_amdgcn_mfma_f32_16x16x32_bf16(z.v, w1f, acc_x, 0, 0, 0);
        // v1x*s2 -> W2 (acc_x)
#pragma unroll
        for (int k = 0; k < 4; ++k)
            z.h[k] = cvt2(A.y * Bv[2*k].x, A.y * Bv[2*k+1].x);
        acc_x = __builtin_amdgcn_mfma_f32_16x16x32_bf16(z.v, w2f, acc_x, 0, 0, 0);
        // cross_x -> W4 (acc_x)
#pragma unroll
        for (int k = 0; k < 4; ++k)
            z.h[k] = cvt2(A.z * Bv[2*k].w   - A.w * Bv[2*k].z,
                          A.z * Bv[2*k+1].w - A.w * Bv[2*k+1].z);
        acc_x = __builtin_amdgcn_mfma_f32_16x16x32_bf16(z.v, w4f, acc_x, 0, 0, 0);

        // s1*v2y -> W1 (acc_y)
#pragma unroll
        for (int k = 0; k < 4; ++k)
            z.h[k] = cvt2(A.x * Bv[2*k].z, A.x * Bv[2*k+1].z);
        acc_y = __builtin_amdgcn_mfma_f32_16x16x32_bf16(z.v, w1f, acc_y, 0, 0, 0);
        // v1y*s2 -> W2 (acc_y)
#pragma unroll
        for (int k = 0; k < 4; ++k)
            z.h[k] = cvt2(A.z * Bv[2*k].x, A.z * Bv[2*k+1].x);
        acc_y = __builtin_amdgcn_mfma_f32_16x16x32_bf16(z.v, w2f, acc_y, 0, 0, 0);
        // cross_y -> W4 (acc_y)
#pragma unroll
        for (int k = 0; k < 4; ++k)
            z.h[k] = cvt2(A.w * Bv[2*k].y   - A.y * Bv[2*k].w,
                          A.w * Bv[2*k+1].y - A.y * Bv[2*k+1].w);
        acc_y = __builtin_amdgcn_mfma_f32_16x16x32_bf16(z.v, w4f, acc_y, 0, 0, 0);

        // s1*v2z -> W1 (acc_z)
#pragma unroll
        for (int k = 0; k < 4; ++k)
            z.h[k] = cvt2(A.x * Bv[2*k].w, A.x * Bv[2*k+1].w);
        acc_z = __builtin_amdgcn_mfma_f32_16x16x32_bf16(z.v, w1f, acc_z, 0, 0, 0);
        // v1z*s2 -> W2 (acc_z)
#pragma unroll
        for (int k = 0; k < 4; ++k)
            z.h[k] = cvt2(A.w * Bv[2*k].x, A.w * Bv[2*k+1].x);
        acc_z = __builtin_amdgcn_mfma_f32_16x16x32_bf16(z.v, w2f, acc_z, 0, 0, 0);
        // cross_z -> W4 (acc_z)
#pragma unroll
        for (int k = 0; k < 4; ++k)
            z.h[k] = cvt2(A.y * Bv[2*k].z   - A.z * Bv[2*k].y,
                          A.y * Bv[2*k+1].z - A.z * Bv[2*k+1].y);
        acc_z = __builtin_amdgcn_mfma_f32_16x16x32_bf16(z.v, w4f, acc_z, 0, 0, 0);
    }

    // ---------- epilogue: segmented reduction over sorted destinations ----------
    __syncthreads();   // everyone done reading sA/sB; pool is now segOut

    // zero segment tiles
    for (int i = t; i < BLK_EDGES * 64; i += 256) segOut[i] = 0.f;

    // wave 0: segment boundaries via ballot over sorted rows
    if (wave == 0) {
        int node = sR[lane];
        int flag = (lane == 0) || (node != sR[lane - 1]);
        unsigned long long mask = __ballot(flag);
        // segment index = (# flags at-or-below me) - 1   [BUGFIX vs round 4]
        int seg = (int)__popcll(mask & ((1ull << lane) - 1ull)) + flag - 1;
        sSeg[lane] = seg;
        if (flag) sSegNode[seg] = node;
        if (lane == 0) sNseg = (int)__popcll(mask);
    }
    __syncthreads();

    // LDS accumulate: D row = q*4 + r (edge), col = m (w)
#pragma unroll
    for (int r = 0; r < 4; ++r) {
        int seg = sSeg[wave * 16 + q * 4 + r];
        float* sp = segOut + seg * 64 + m * 4;
        atomicAdd(sp + 0, acc_s[r]);
        atomicAdd(sp + 1, acc_x[r]);
        atomicAdd(sp + 2, acc_y[r]);
        atomicAdd(sp + 3, acc_z[r]);
    }
    __syncthreads();

    // one global atomic set per distinct node
    int nseg = sNseg;
    for (int idx = t; idx < nseg * 64; idx += 256) {
        int s = idx >> 6, f = idx & 63;
        atomicAdd(out + (size_t)sSegNode[s] * 64 + f, segOut[idx]);
    }
}

// -------------------- gate: s' = silu(s), v' = v * sigmoid(s)
__global__ void gate_kernel(float4* __restrict__ feat) {
    int i = blockIdx.x * blockDim.x + threadIdx.x;   // (n*16 + w)
    if (i >= N_NODES * 16) return;
    float4 f = feat[i];
    float g = 1.f / (1.f + __expf(-f.x));
    feat[i] = make_float4(f.x * g, f.y * g, f.z * g, f.w * g);
}

// -------------------- readout
__global__ void readout_kernel(const float4* __restrict__ feat,
                               const int* __restrict__ batch_idx,
                               const float* __restrict__ w_out,
                               float* __restrict__ energy) {
    __shared__ float bins[N_GRAPHS];
    int t = threadIdx.x;
    if (t < N_GRAPHS) bins[t] = 0.f;
    __syncthreads();
    int n = blockIdx.x * blockDim.x + t;
    if (n < N_NODES) {
        const float4* f = feat + (size_t)n * 16;
        float acc = 0.f;
#pragma unroll
        for (int w = 0; w < 16; ++w) acc += f[w].x * w_out[w];
        atomicAdd(&bins[batch_idx[n]], acc * INV_LIN_OUT);
    }
    __syncthreads();
    if (t < N_GRAPHS) atomicAdd(&energy[t], bins[t]);
}

extern "C" void kernel_launch(void* const* d_in, const int* in_sizes, int n_in,
                              void* d_out, int out_size, void* d_ws, size_t ws_size,
                              hipStream_t stream) {
    const float* x         = (const float*)d_in[0];
    const int*   row       = (const int*)d_in[1];
    const int*   col       = (const int*)d_in[2];
    const int*   batch_idx = (const int*)d_in[3];
    const float* w_in0     = (const float*)d_in[4];
    const float* w_in1     = (const float*)d_in[5];
    const float* tp_w      = (const float*)d_in[6];   // [3][5][16][16][16]
    const float* w_out0    = (const float*)d_in[7];
    float* energy = (float*)d_out;

    // workspace layout (28.1 MB total; round-3-proven 25.7 MB + 2.4 MB)
    float* bufA = (float*)d_ws;                            // [N][64] f32
    float* bufB = bufA + (size_t)N_NODES * 64;             // [N][64] f32
    short* wbf  = (short*)(bufB + (size_t)N_NODES * 64);   // [3][5][8][64][8] bf16
    int* sortedRC = (int*)(wbf + 3 * 20480);               // [E] packed (row | col<<16)
    // transient sort scratch aliased into bufB (dead until layer-0 memset)
    int* counts  = (int*)bufB;
    int* cursor  = counts + N_NODES;
    int* partial = cursor + N_NODES;
    int* partOff = partial + 256;

    // build destination-sorted edge list (row is static across layers)
    hipMemsetAsync(counts, 0, N_NODES * sizeof(int), stream);
    hist_kernel<<<(N_EDGES + 255) / 256, 256, 0, stream>>>(row, counts);
    scan_part_kernel<<<NPART, 256, 0, stream>>>(counts, partial);
    scan_partials_kernel<<<1, 256, 0, stream>>>(partial, partOff);
    scan_final_kernel<<<NPART, 256, 0, stream>>>(counts, partOff, cursor);
    scatter_kernel<<<(N_EDGES + 255) / 256, 256, 0, stream>>>(row, col, cursor, sortedRC);

    swizzle_w_kernel<<<(3 * 20480 + 255) / 256, 256, 0, stream>>>(tp_w, wbf);
    proj_kernel<<<(N_NODES + 255) / 256, 256, 0, stream>>>(x, w_in0, w_in1, (float4*)bufA);

    float* fin = bufA;
    float* fout = bufB;
    for (int l = 0; l < 3; ++l) {
        hipMemsetAsync(fout, 0, (size_t)N_NODES * 64 * sizeof(float), stream);
        edge_tp_kernel<<<N_EDGES / BLK_EDGES, 256, 0, stream>>>(
            (const float4*)fin, fout, sortedRC, wbf + (size_t)l * 20480);
        gate_kernel<<<(N_NODES * 16 + 255) / 256, 256, 0, stream>>>((float4*)fout);
        float* t = fin; fin = fout; fout = t;
    }

    hipMemsetAsync(energy, 0, N_GRAPHS * sizeof(float), stream);
    readout_kernel<<<(N_NODES + 255) / 256, 256, 0, stream>>>(
        (const float4*)fin, batch_idx, w_out0, energy);
}

// Round 6
// 1071.493 us; speedup vs baseline: 71.3512x; 1.0861x over previous
//
#include <hip/hip_runtime.h>
#include <hip/hip_bf16.h>

#define N_NODES 50000
#define N_EDGES 600000
#define N_GRAPHS 64
#define NPART 196      // ceil(50000/256) scan partials

// constants
#define INV_LIN_IN  0.35355339059327373f   // 1/sqrt(8)
#define INV_LIN_OUT 0.25f                  // 1/sqrt(16)
#define C_INV_S3    0.5773502691896258f    // 1/sqrt(3)
#define C_INV_S2    0.7071067811865476f    // 1/sqrt(2)
#define C_NORM_S    0.04419417382415922f   // 1/sqrt(512)
#define C_NORM_V    0.036084391824351615f  // 1/sqrt(768)

typedef __attribute__((ext_vector_type(8))) short short8;
typedef __attribute__((ext_vector_type(4))) float f32x4;

// ==================== sort edges by destination (row); pack (row,col) in one int ====
__global__ void hist_kernel(const int* __restrict__ row, int* __restrict__ counts) {
    int e = blockIdx.x * 256 + threadIdx.x;
    if (e < N_EDGES) atomicAdd(&counts[row[e]], 1);
}

__global__ void scan_part_kernel(const int* __restrict__ counts, int* __restrict__ partial) {
    __shared__ int sm[256];
    int t = threadIdx.x;
    int i = blockIdx.x * 256 + t;
    sm[t] = (i < N_NODES) ? counts[i] : 0;
    __syncthreads();
    for (int s = 128; s > 0; s >>= 1) {
        if (t < s) sm[t] += sm[t + s];
        __syncthreads();
    }
    if (t == 0) partial[blockIdx.x] = sm[0];
}

__global__ void scan_partials_kernel(const int* __restrict__ partial, int* __restrict__ partOff) {
    __shared__ int sm[256];
    int t = threadIdx.x;
    int v = (t < NPART) ? partial[t] : 0;
    sm[t] = v;
    __syncthreads();
    for (int s = 1; s < 256; s <<= 1) {
        int add = (t >= s) ? sm[t - s] : 0;
        __syncthreads();
        sm[t] += add;
        __syncthreads();
    }
    if (t < NPART) partOff[t] = sm[t] - v;   // exclusive
}

__global__ void scan_final_kernel(const int* __restrict__ counts,
                                  const int* __restrict__ partOff,
                                  int* __restrict__ cursor) {
    __shared__ int sm[256];
    int t = threadIdx.x;
    int i = blockIdx.x * 256 + t;
    int v = (i < N_NODES) ? counts[i] : 0;
    sm[t] = v;
    __syncthreads();
    for (int s = 1; s < 256; s <<= 1) {
        int add = (t >= s) ? sm[t - s] : 0;
        __syncthreads();
        sm[t] += add;
        __syncthreads();
    }
    if (i < N_NODES) cursor[i] = sm[t] - v + partOff[blockIdx.x];   // exclusive offsets
}

__global__ void scatter_kernel(const int* __restrict__ row, const int* __restrict__ col,
                               int* __restrict__ cursor, int* __restrict__ sortedRC) {
    int e = blockIdx.x * 256 + threadIdx.x;
    if (e < N_EDGES) {
        int n = row[e];
        int pos = atomicAdd(&cursor[n], 1);
        sortedRC[pos] = n | (col[e] << 16);   // node ids < 50000 < 65536
    }
}

// -------------------- input projection: x[N,32] -> feat[N][16] float4(s,vx,vy,vz)
__global__ void proj_kernel(const float* __restrict__ x,
                            const float* __restrict__ w_in0,
                            const float* __restrict__ w_in1,
                            float4* __restrict__ out) {
    int n = blockIdx.x * blockDim.x + threadIdx.x;
    if (n >= N_NODES) return;
    const float* xp = x + (size_t)n * 32;
    float xs[8], xvx[8], xvy[8], xvz[8];
#pragma unroll
    for (int u = 0; u < 8; ++u) xs[u] = xp[u];
#pragma unroll
    for (int u = 0; u < 8; ++u) {
        xvx[u] = xp[8 + 3 * u + 0];
        xvy[u] = xp[8 + 3 * u + 1];
        xvz[u] = xp[8 + 3 * u + 2];
    }
#pragma unroll
    for (int w = 0; w < 16; ++w) {
        float s = 0.f, vx = 0.f, vy = 0.f, vz = 0.f;
#pragma unroll
        for (int u = 0; u < 8; ++u) {
            float a0 = w_in0[u * 16 + w];
            float a1 = w_in1[u * 16 + w];
            s  += xs[u]  * a0;
            vx += xvx[u] * a1;
            vy += xvy[u] * a1;
            vz += xvz[u] * a1;
        }
        out[(size_t)n * 16 + w] =
            make_float4(s * INV_LIN_IN, vx * INV_LIN_IN, vy * INV_LIN_IN, vz * INV_LIN_IN);
    }
}

// -------------------- weight pre-swizzle: fp32 [3][5][16(u)][16(v)][16(w)]
// -> bf16 in MFMA B-fragment order, norm constants folded.
__global__ void swizzle_w_kernel(const float* __restrict__ tp_w, short* __restrict__ wbf) {
    int i = blockIdx.x * 256 + threadIdx.x;
    if (i >= 3 * 20480) return;
    int j    = i & 7;
    int t1   = i >> 3;
    int lane = t1 & 63;
    int t2   = t1 >> 6;
    int c    = t2 & 7;
    int t3   = t2 >> 3;
    int p    = t3 % 5;
    int l    = t3 / 5;
    int kk = c * 32 + (lane >> 4) * 8 + j;
    int u = kk >> 4, v = kk & 15, n = lane & 15;
    float scale;
    if      (p == 0) scale = C_NORM_S;
    else if (p == 3) scale = C_INV_S3 * C_NORM_S;
    else if (p == 4) scale = C_INV_S2 * C_NORM_V;
    else             scale = C_NORM_V;   // p==1, p==2
    float val = tp_w[(size_t)(l * 5 + p) * 4096 + u * 256 + v * 16 + n] * scale;
    __hip_bfloat16 h = __float2bfloat16(val);
    wbf[i] = *reinterpret_cast<short*>(&h);
}

static __device__ inline __hip_bfloat162 cvt2(float x, float y) {
    return __float22bfloat162_rn(make_float2(x, y));
}

// -------------------- edge tensor product via MFMA, barrier-free
// Each wave owns 16 sorted edges. B-side features hoisted to registers; A per
// chunk from L2. Wave-local segmented epilogue (no __syncthreads anywhere).
__global__ __launch_bounds__(256, 4)
void edge_tp_kernel(const float4* __restrict__ feat,
                    float* __restrict__ out,          // [N][16][4] floats
                    const int* __restrict__ sortedRC,
                    const short* __restrict__ wbf) {
    __shared__ float segOut[4][16][64];   // per-wave segment pools, 16 KB

    const int t = threadIdx.x;
    const int lane = t & 63;
    const int wave = t >> 6;
    const int q = lane >> 4;        // quad 0..3
    const int m = lane & 15;        // edge-in-tile / w column
    const int tileBase = (blockIdx.x * 4 + wave) * 16;

    // every lane holds edge m's (row,col)
    int rc = sortedRC[tileBase + m];
    int myR = rc & 0xFFFF;
    int myC = (int)(((unsigned)rc) >> 16);

    // zero this wave's segment pool (wave-private; no barrier needed)
#pragma unroll
    for (int i = 0; i < 16; ++i) segOut[wave][i][lane] = 0.f;

    // hoist B fragment source: feat[myC][v0 .. v0+7] -> registers (loop-invariant)
    const int v0 = (q & 1) * 8;
    const float4* bp = feat + (size_t)myC * 16 + v0;
    float4 Bv[8];
#pragma unroll
    for (int k = 0; k < 8; ++k) Bv[k] = bp[k];

    const float4* ap = feat + (size_t)myR * 16;

    f32x4 acc_s = {0.f, 0.f, 0.f, 0.f};
    f32x4 acc_x = {0.f, 0.f, 0.f, 0.f};
    f32x4 acc_y = {0.f, 0.f, 0.f, 0.f};
    f32x4 acc_z = {0.f, 0.f, 0.f, 0.f};

    const short8* wf = (const short8*)wbf;   // frag index: (p*8 + c)*64 + lane

#pragma unroll 2
    for (int c = 0; c < 8; ++c) {
        short8 w0f = wf[(0 * 8 + c) * 64 + lane];
        short8 w1f = wf[(1 * 8 + c) * 64 + lane];
        short8 w2f = wf[(2 * 8 + c) * 64 + lane];
        short8 w3f = wf[(3 * 8 + c) * 64 + lane];
        short8 w4f = wf[(4 * 8 + c) * 64 + lane];

        float4 A = ap[2 * c + (q >> 1)];   // L2-hot (sorted rows)

        union { short8 v; __hip_bfloat162 h[4]; } z;

        // ss -> W0 (acc_s)
#pragma unroll
        for (int k = 0; k < 4; ++k)
            z.h[k] = cvt2(A.x * Bv[2*k].x, A.x * Bv[2*k+1].x);
        acc_s = __builtin_amdgcn_mfma_f32_16x16x32_bf16(z.v, w0f, acc_s, 0, 0, 0);

        // dot(v1,v2) -> W3 (acc_s)
#pragma unroll
        for (int k = 0; k < 4; ++k)
            z.h[k] = cvt2(A.y * Bv[2*k].y   + A.z * Bv[2*k].z   + A.w * Bv[2*k].w,
                          A.y * Bv[2*k+1].y + A.z * Bv[2*k+1].z + A.w * Bv[2*k+1].w);
        acc_s = __builtin_amdgcn_mfma_f32_16x16x32_bf16(z.v, w3f, acc_s, 0, 0, 0);

        // s1*v2x -> W1 (acc_x)
#pragma unroll
        for (int k = 0; k < 4; ++k)
            z.h[k] = cvt2(A.x * Bv[2*k].y, A.x * Bv[2*k+1].y);
        acc_x = __builtin_amdgcn_mfma_f32_16x16x32_bf16(z.v, w1f, acc_x, 0, 0, 0);
        // v1x*s2 -> W2 (acc_x)
#pragma unroll
        for (int k = 0; k < 4; ++k)
            z.h[k] = cvt2(A.y * Bv[2*k].x, A.y * Bv[2*k+1].x);
        acc_x = __builtin_amdgcn_mfma_f32_16x16x32_bf16(z.v, w2f, acc_x, 0, 0, 0);
        // cross_x -> W4 (acc_x)
#pragma unroll
        for (int k = 0; k < 4; ++k)
            z.h[k] = cvt2(A.z * Bv[2*k].w   - A.w * Bv[2*k].z,
                          A.z * Bv[2*k+1].w - A.w * Bv[2*k+1].z);
        acc_x = __builtin_amdgcn_mfma_f32_16x16x32_bf16(z.v, w4f, acc_x, 0, 0, 0);

        // s1*v2y -> W1 (acc_y)
#pragma unroll
        for (int k = 0; k < 4; ++k)
            z.h[k] = cvt2(A.x * Bv[2*k].z, A.x * Bv[2*k+1].z);
        acc_y = __builtin_amdgcn_mfma_f32_16x16x32_bf16(z.v, w1f, acc_y, 0, 0, 0);
        // v1y*s2 -> W2 (acc_y)
#pragma unroll
        for (int k = 0; k < 4; ++k)
            z.h[k] = cvt2(A.z * Bv[2*k].x, A.z * Bv[2*k+1].x);
        acc_y = __builtin_amdgcn_mfma_f32_16x16x32_bf16(z.v, w2f, acc_y, 0, 0, 0);
        // cross_y -> W4 (acc_y)
#pragma unroll
        for (int k = 0; k < 4; ++k)
            z.h[k] = cvt2(A.w * Bv[2*k].y   - A.y * Bv[2*k].w,
                          A.w * Bv[2*k+1].y - A.y * Bv[2*k+1].w);
        acc_y = __builtin_amdgcn_mfma_f32_16x16x32_bf16(z.v, w4f, acc_y, 0, 0, 0);

        // s1*v2z -> W1 (acc_z)
#pragma unroll
        for (int k = 0; k < 4; ++k)
            z.h[k] = cvt2(A.x * Bv[2*k].w, A.x * Bv[2*k+1].w);
        acc_z = __builtin_amdgcn_mfma_f32_16x16x32_bf16(z.v, w1f, acc_z, 0, 0, 0);
        // v1z*s2 -> W2 (acc_z)
#pragma unroll
        for (int k = 0; k < 4; ++k)
            z.h[k] = cvt2(A.w * Bv[2*k].x, A.w * Bv[2*k+1].x);
        acc_z = __builtin_amdgcn_mfma_f32_16x16x32_bf16(z.v, w2f, acc_z, 0, 0, 0);
        // cross_z -> W4 (acc_z)
#pragma unroll
        for (int k = 0; k < 4; ++k)
            z.h[k] = cvt2(A.y * Bv[2*k].z   - A.z * Bv[2*k].y,
                          A.y * Bv[2*k+1].z - A.z * Bv[2*k+1].y);
        acc_z = __builtin_amdgcn_mfma_f32_16x16x32_bf16(z.v, w4f, acc_z, 0, 0, 0);
    }

    // ---------- wave-local segmented epilogue (no barriers) ----------
    // previous edge's row: lane-1 holds edge m-1 (m==0 boundary forced)
    int prevR = __shfl(myR, (lane + 63) & 63);
    int flag = (m == 0) || (myR != prevR);
    unsigned long long bal = __ballot(flag != 0);
    unsigned mask16 = (unsigned)(bal & 0xFFFFull);   // identical across quads

    // accumulate D rows into per-segment LDS tiles
    // D row r -> edge ei = q*4 + r, col = m (w)
#pragma unroll
    for (int r = 0; r < 4; ++r) {
        int ei = q * 4 + r;
        int seg = __popc(mask16 & ((2u << ei) - 1u)) - 1;
        float* sp = &segOut[wave][seg][m * 4];
        atomicAdd(sp + 0, acc_s[r]);
        atomicAdd(sp + 1, acc_x[r]);
        atomicAdd(sp + 2, acc_y[r]);
        atomicAdd(sp + 3, acc_z[r]);
    }

    // one global atomic set per distinct destination node
    int nseg = __popc(mask16);
    unsigned rem = mask16;
    for (int s = 0; s < nseg; ++s) {
        int fe = __ffs(rem) - 1;   // first edge of segment s (uniform)
        rem &= rem - 1;
        int node = __shfl(myR, fe);
        atomicAdd(out + (size_t)node * 64 + lane, segOut[wave][s][lane]);
    }
}

// -------------------- gate: s' = silu(s), v' = v * sigmoid(s)
__global__ void gate_kernel(float4* __restrict__ feat) {
    int i = blockIdx.x * blockDim.x + threadIdx.x;   // (n*16 + w)
    if (i >= N_NODES * 16) return;
    float4 f = feat[i];
    float g = 1.f / (1.f + __expf(-f.x));
    feat[i] = make_float4(f.x * g, f.y * g, f.z * g, f.w * g);
}

// -------------------- readout
__global__ void readout_kernel(const float4* __restrict__ feat,
                               const int* __restrict__ batch_idx,
                               const float* __restrict__ w_out,
                               float* __restrict__ energy) {
    __shared__ float bins[N_GRAPHS];
    int t = threadIdx.x;
    if (t < N_GRAPHS) bins[t] = 0.f;
    __syncthreads();
    int n = blockIdx.x * blockDim.x + t;
    if (n < N_NODES) {
        const float4* f = feat + (size_t)n * 16;
        float acc = 0.f;
#pragma unroll
        for (int w = 0; w < 16; ++w) acc += f[w].x * w_out[w];
        atomicAdd(&bins[batch_idx[n]], acc * INV_LIN_OUT);
    }
    __syncthreads();
    if (t < N_GRAPHS) atomicAdd(&energy[t], bins[t]);
}

extern "C" void kernel_launch(void* const* d_in, const int* in_sizes, int n_in,
                              void* d_out, int out_size, void* d_ws, size_t ws_size,
                              hipStream_t stream) {
    const float* x         = (const float*)d_in[0];
    const int*   row       = (const int*)d_in[1];
    const int*   col       = (const int*)d_in[2];
    const int*   batch_idx = (const int*)d_in[3];
    const float* w_in0     = (const float*)d_in[4];
    const float* w_in1     = (const float*)d_in[5];
    const float* tp_w      = (const float*)d_in[6];   // [3][5][16][16][16]
    const float* w_out0    = (const float*)d_in[7];
    float* energy = (float*)d_out;

    // workspace layout (28.1 MB total)
    float* bufA = (float*)d_ws;                            // [N][64] f32
    float* bufB = bufA + (size_t)N_NODES * 64;             // [N][64] f32
    short* wbf  = (short*)(bufB + (size_t)N_NODES * 64);   // [3][5][8][64][8] bf16
    int* sortedRC = (int*)(wbf + 3 * 20480);               // [E] packed (row | col<<16)
    // transient sort scratch aliased into bufB (dead until layer-0 memset)
    int* counts  = (int*)bufB;
    int* cursor  = counts + N_NODES;
    int* partial = cursor + N_NODES;
    int* partOff = partial + 256;

    // build destination-sorted edge list (row is static across layers)
    hipMemsetAsync(counts, 0, N_NODES * sizeof(int), stream);
    hist_kernel<<<(N_EDGES + 255) / 256, 256, 0, stream>>>(row, counts);
    scan_part_kernel<<<NPART, 256, 0, stream>>>(counts, partial);
    scan_partials_kernel<<<1, 256, 0, stream>>>(partial, partOff);
    scan_final_kernel<<<NPART, 256, 0, stream>>>(counts, partOff, cursor);
    scatter_kernel<<<(N_EDGES + 255) / 256, 256, 0, stream>>>(row, col, cursor, sortedRC);

    swizzle_w_kernel<<<(3 * 20480 + 255) / 256, 256, 0, stream>>>(tp_w, wbf);
    proj_kernel<<<(N_NODES + 255) / 256, 256, 0, stream>>>(x, w_in0, w_in1, (float4*)bufA);

    float* fin = bufA;
    float* fout = bufB;
    for (int l = 0; l < 3; ++l) {
        hipMemsetAsync(fout, 0, (size_t)N_NODES * 64 * sizeof(float), stream);
        edge_tp_kernel<<<N_EDGES / 64, 256, 0, stream>>>(
            (const float4*)fin, fout, sortedRC, wbf + (size_t)l * 20480);
        gate_kernel<<<(N_NODES * 16 + 255) / 256, 256, 0, stream>>>((float4*)fout);
        float* t = fin; fin = fout; fout = t;
    }

    hipMemsetAsync(energy, 0, N_GRAPHS * sizeof(float), stream);
    readout_kernel<<<(N_NODES + 255) / 256, 256, 0, stream>>>(
        (const float4*)fin, batch_idx, w_out0, energy);
}

// Round 7
// 647.792 us; speedup vs baseline: 118.0198x; 1.6541x over previous
//
#include <hip/hip_runtime.h>
#include <hip/hip_bf16.h>

#define N_NODES 50000
#define N_EDGES 600000
#define N_GRAPHS 64
#define N_TILES (N_EDGES / 16)   // 37500 wave-tiles
#define NPART 196                // ceil(50000/256) scan partials

// constants
#define INV_LIN_IN  0.35355339059327373f   // 1/sqrt(8)
#define INV_LIN_OUT 0.25f                  // 1/sqrt(16)
#define C_INV_S3    0.5773502691896258f    // 1/sqrt(3)
#define C_INV_S2    0.7071067811865476f    // 1/sqrt(2)
#define C_NORM_S    0.04419417382415922f   // 1/sqrt(512)
#define C_NORM_V    0.036084391824351615f  // 1/sqrt(768)

typedef __attribute__((ext_vector_type(8))) short short8;
typedef __attribute__((ext_vector_type(4))) float f32x4;

// ==================== sort edges by destination (row); pack (row,col) in one int ====
__global__ void hist_kernel(const int* __restrict__ row, int* __restrict__ counts) {
    int e = blockIdx.x * 256 + threadIdx.x;
    if (e < N_EDGES) atomicAdd(&counts[row[e]], 1);
}

__global__ void scan_part_kernel(const int* __restrict__ counts, int* __restrict__ partial) {
    __shared__ int sm[256];
    int t = threadIdx.x;
    int i = blockIdx.x * 256 + t;
    sm[t] = (i < N_NODES) ? counts[i] : 0;
    __syncthreads();
    for (int s = 128; s > 0; s >>= 1) {
        if (t < s) sm[t] += sm[t + s];
        __syncthreads();
    }
    if (t == 0) partial[blockIdx.x] = sm[0];
}

__global__ void scan_partials_kernel(const int* __restrict__ partial, int* __restrict__ partOff) {
    __shared__ int sm[256];
    int t = threadIdx.x;
    int v = (t < NPART) ? partial[t] : 0;
    sm[t] = v;
    __syncthreads();
    for (int s = 1; s < 256; s <<= 1) {
        int add = (t >= s) ? sm[t - s] : 0;
        __syncthreads();
        sm[t] += add;
        __syncthreads();
    }
    if (t < NPART) partOff[t] = sm[t] - v;   // exclusive
}

__global__ void scan_final_kernel(const int* __restrict__ counts,
                                  const int* __restrict__ partOff,
                                  int* __restrict__ cursor) {
    __shared__ int sm[256];
    int t = threadIdx.x;
    int i = blockIdx.x * 256 + t;
    int v = (i < N_NODES) ? counts[i] : 0;
    sm[t] = v;
    __syncthreads();
    for (int s = 1; s < 256; s <<= 1) {
        int add = (t >= s) ? sm[t - s] : 0;
        __syncthreads();
        sm[t] += add;
        __syncthreads();
    }
    if (i < N_NODES) cursor[i] = sm[t] - v + partOff[blockIdx.x];   // exclusive offsets
}

__global__ void scatter_kernel(const int* __restrict__ row, const int* __restrict__ col,
                               int* __restrict__ cursor, int* __restrict__ sortedRC) {
    int e = blockIdx.x * 256 + threadIdx.x;
    if (e < N_EDGES) {
        int n = row[e];
        int pos = atomicAdd(&cursor[n], 1);
        sortedRC[pos] = n | (col[e] << 16);   // node ids < 50000 < 65536
    }
}

// -------------------- input projection: x[N,32] -> feat[N][16] float4(s,vx,vy,vz)
__global__ void proj_kernel(const float* __restrict__ x,
                            const float* __restrict__ w_in0,
                            const float* __restrict__ w_in1,
                            float4* __restrict__ out) {
    int n = blockIdx.x * blockDim.x + threadIdx.x;
    if (n >= N_NODES) return;
    const float* xp = x + (size_t)n * 32;
    float xs[8], xvx[8], xvy[8], xvz[8];
#pragma unroll
    for (int u = 0; u < 8; ++u) xs[u] = xp[u];
#pragma unroll
    for (int u = 0; u < 8; ++u) {
        xvx[u] = xp[8 + 3 * u + 0];
        xvy[u] = xp[8 + 3 * u + 1];
        xvz[u] = xp[8 + 3 * u + 2];
    }
#pragma unroll
    for (int w = 0; w < 16; ++w) {
        float s = 0.f, vx = 0.f, vy = 0.f, vz = 0.f;
#pragma unroll
        for (int u = 0; u < 8; ++u) {
            float a0 = w_in0[u * 16 + w];
            float a1 = w_in1[u * 16 + w];
            s  += xs[u]  * a0;
            vx += xvx[u] * a1;
            vy += xvy[u] * a1;
            vz += xvz[u] * a1;
        }
        out[(size_t)n * 16 + w] =
            make_float4(s * INV_LIN_IN, vx * INV_LIN_IN, vy * INV_LIN_IN, vz * INV_LIN_IN);
    }
}

// -------------------- weight pre-swizzle: fp32 [3][5][16(u)][16(v)][16(w)]
// -> bf16 in MFMA B-fragment order, norm constants folded.
__global__ void swizzle_w_kernel(const float* __restrict__ tp_w, short* __restrict__ wbf) {
    int i = blockIdx.x * 256 + threadIdx.x;
    if (i >= 3 * 20480) return;
    int j    = i & 7;
    int t1   = i >> 3;
    int lane = t1 & 63;
    int t2   = t1 >> 6;
    int c    = t2 & 7;
    int t3   = t2 >> 3;
    int p    = t3 % 5;
    int l    = t3 / 5;
    int kk = c * 32 + (lane >> 4) * 8 + j;
    int u = kk >> 4, v = kk & 15, n = kk; n = lane & 15;
    float scale;
    if      (p == 0) scale = C_NORM_S;
    else if (p == 3) scale = C_INV_S3 * C_NORM_S;
    else if (p == 4) scale = C_INV_S2 * C_NORM_V;
    else             scale = C_NORM_V;   // p==1, p==2
    float val = tp_w[(size_t)(l * 5 + p) * 4096 + u * 256 + v * 16 + n] * scale;
    __hip_bfloat16 h = __float2bfloat16(val);
    wbf[i] = *reinterpret_cast<short*>(&h);
}

static __device__ inline __hip_bfloat162 cvt2(float x, float y) {
    return __float22bfloat162_rn(make_float2(x, y));
}

// -------------------- edge tensor product: persistent waves, weights in LDS
// Each wave owns a contiguous range of 16-edge tiles from the dest-sorted edge
// list. Weights (full layer, 40KB) staged in LDS once per block. Epilogue is a
// cross-quad shuffle reduction + one atomic per (segment, lane).
__global__ __launch_bounds__(256, 4)
void edge_tp_kernel(const float4* __restrict__ feat,
                    float* __restrict__ out,          // [N][16][4] floats
                    const int* __restrict__ sortedRC,
                    const short* __restrict__ wbf) {
    __shared__ short8 sW[2560];   // 40 KB: whole layer in B-frag order

    const int t = threadIdx.x;
    // stage weights (linear copy), once per persistent block
    {
        const int4* src = (const int4*)wbf;
        int4* dst = (int4*)sW;
#pragma unroll
        for (int i = 0; i < 10; ++i) dst[t + 256 * i] = src[t + 256 * i];
    }
    __syncthreads();   // the only barrier; waves independent hereafter

    const int lane = t & 63;
    const int wave = t >> 6;
    const int q = lane >> 4;        // quad 0..3
    const int m = lane & 15;        // edge-in-tile / w column
    const int v0 = (q & 1) * 8;

    // contiguous tile range for this wave (locality: sorted rows)
    const int gw = blockIdx.x * 4 + wave;
    const int nw = gridDim.x * 4;
    int tile = (int)(((long long)gw * N_TILES) / nw);
    const int tileEnd = (int)(((long long)(gw + 1) * N_TILES) / nw);
    if (tile >= tileEnd) return;

    int rc = sortedRC[tile * 16 + m];
    float4 Bv[8];
    {
        const float4* bp = feat + (size_t)(((unsigned)rc) >> 16) * 16 + v0;
#pragma unroll
        for (int k = 0; k < 8; ++k) Bv[k] = bp[k];
    }

    for (; tile < tileEnd; ++tile) {
        const int myR = rc & 0xFFFF;
        // next tile's rc: issue early, consumed after the chunk loop
        const int nt = tile + 1;
        const int nrc = (nt < tileEnd) ? sortedRC[nt * 16 + m] : rc;

        f32x4 acc_s = {0.f, 0.f, 0.f, 0.f};
        f32x4 acc_x = {0.f, 0.f, 0.f, 0.f};
        f32x4 acc_y = {0.f, 0.f, 0.f, 0.f};
        f32x4 acc_z = {0.f, 0.f, 0.f, 0.f};

        const float4* ap = feat + (size_t)myR * 16;

#pragma unroll 2
        for (int c = 0; c < 8; ++c) {
            short8 w0f = sW[(0 * 8 + c) * 64 + lane];
            short8 w1f = sW[(1 * 8 + c) * 64 + lane];
            short8 w2f = sW[(2 * 8 + c) * 64 + lane];
            short8 w3f = sW[(3 * 8 + c) * 64 + lane];
            short8 w4f = sW[(4 * 8 + c) * 64 + lane];

            float4 A = ap[2 * c + (q >> 1)];   // L1-hot (sorted rows)

            union { short8 v; __hip_bfloat162 h[4]; } z;

            // ss -> W0 (acc_s)
#pragma unroll
            for (int k = 0; k < 4; ++k)
                z.h[k] = cvt2(A.x * Bv[2*k].x, A.x * Bv[2*k+1].x);
            acc_s = __builtin_amdgcn_mfma_f32_16x16x32_bf16(z.v, w0f, acc_s, 0, 0, 0);

            // dot(v1,v2) -> W3 (acc_s)
#pragma unroll
            for (int k = 0; k < 4; ++k)
                z.h[k] = cvt2(A.y * Bv[2*k].y   + A.z * Bv[2*k].z   + A.w * Bv[2*k].w,
                              A.y * Bv[2*k+1].y + A.z * Bv[2*k+1].z + A.w * Bv[2*k+1].w);
            acc_s = __builtin_amdgcn_mfma_f32_16x16x32_bf16(z.v, w3f, acc_s, 0, 0, 0);

            // s1*v2x -> W1 (acc_x)
#pragma unroll
            for (int k = 0; k < 4; ++k)
                z.h[k] = cvt2(A.x * Bv[2*k].y, A.x * Bv[2*k+1].y);
            acc_x = __builtin_amdgcn_mfma_f32_16x16x32_bf16(z.v, w1f, acc_x, 0, 0, 0);
            // v1x*s2 -> W2 (acc_x)
#pragma unroll
            for (int k = 0; k < 4; ++k)
                z.h[k] = cvt2(A.y * Bv[2*k].x, A.y * Bv[2*k+1].x);
            acc_x = __builtin_amdgcn_mfma_f32_16x16x32_bf16(z.v, w2f, acc_x, 0, 0, 0);
            // cross_x -> W4 (acc_x)
#pragma unroll
            for (int k = 0; k < 4; ++k)
                z.h[k] = cvt2(A.z * Bv[2*k].w   - A.w * Bv[2*k].z,
                              A.z * Bv[2*k+1].w - A.w * Bv[2*k+1].z);
            acc_x = __builtin_amdgcn_mfma_f32_16x16x32_bf16(z.v, w4f, acc_x, 0, 0, 0);

            // s1*v2y -> W1 (acc_y)
#pragma unroll
            for (int k = 0; k < 4; ++k)
                z.h[k] = cvt2(A.x * Bv[2*k].z, A.x * Bv[2*k+1].z);
            acc_y = __builtin_amdgcn_mfma_f32_16x16x32_bf16(z.v, w1f, acc_y, 0, 0, 0);
            // v1y*s2 -> W2 (acc_y)
#pragma unroll
            for (int k = 0; k < 4; ++k)
                z.h[k] = cvt2(A.z * Bv[2*k].x, A.z * Bv[2*k+1].x);
            acc_y = __builtin_amdgcn_mfma_f32_16x16x32_bf16(z.v, w2f, acc_y, 0, 0, 0);
            // cross_y -> W4 (acc_y)
#pragma unroll
            for (int k = 0; k < 4; ++k)
                z.h[k] = cvt2(A.w * Bv[2*k].y   - A.y * Bv[2*k].w,
                              A.w * Bv[2*k+1].y - A.y * Bv[2*k+1].w);
            acc_y = __builtin_amdgcn_mfma_f32_16x16x32_bf16(z.v, w4f, acc_y, 0, 0, 0);

            // s1*v2z -> W1 (acc_z)
#pragma unroll
            for (int k = 0; k < 4; ++k)
                z.h[k] = cvt2(A.x * Bv[2*k].w, A.x * Bv[2*k+1].w);
            acc_z = __builtin_amdgcn_mfma_f32_16x16x32_bf16(z.v, w1f, acc_z, 0, 0, 0);
            // v1z*s2 -> W2 (acc_z)
#pragma unroll
            for (int k = 0; k < 4; ++k)
                z.h[k] = cvt2(A.w * Bv[2*k].x, A.w * Bv[2*k+1].x);
            acc_z = __builtin_amdgcn_mfma_f32_16x16x32_bf16(z.v, w2f, acc_z, 0, 0, 0);
            // cross_z -> W4 (acc_z)
#pragma unroll
            for (int k = 0; k < 4; ++k)
                z.h[k] = cvt2(A.y * Bv[2*k].z   - A.z * Bv[2*k].y,
                              A.y * Bv[2*k+1].z - A.z * Bv[2*k+1].y);
            acc_z = __builtin_amdgcn_mfma_f32_16x16x32_bf16(z.v, w4f, acc_z, 0, 0, 0);
        }

        // prefetch next tile's B into the same registers (epilogue doesn't use Bv)
        {
            const float4* nbp = feat + (size_t)(((unsigned)nrc) >> 16) * 16 + v0;
#pragma unroll
            for (int k = 0; k < 8; ++k) Bv[k] = nbp[k];
        }

        // ---------- wave-local segmented epilogue (shuffle reduction, no LDS) ----------
        int prevR = __shfl(myR, (lane + 63) & 63);
        int flag = (m == 0) || (myR != prevR);
        unsigned long long bal = __ballot(flag != 0);
        unsigned mask16 = (unsigned)(bal & 0xFFFFull);   // identical across quads

        int nseg = __popc(mask16);
        unsigned rem = mask16;
        for (int s = 0; s < nseg; ++s) {
            int lo = __ffs(rem) - 1;
            rem &= rem - 1;
            int hi = rem ? (__ffs(rem) - 1) : 16;
            float ps = 0.f, px = 0.f, py = 0.f, pz = 0.f;
#pragma unroll
            for (int r = 0; r < 4; ++r) {
                int ei = q * 4 + r;
                bool in = (ei >= lo) && (ei < hi);
                ps += in ? acc_s[r] : 0.f;
                px += in ? acc_x[r] : 0.f;
                py += in ? acc_y[r] : 0.f;
                pz += in ? acc_z[r] : 0.f;
            }
            ps += __shfl_xor(ps, 16); ps += __shfl_xor(ps, 32);
            px += __shfl_xor(px, 16); px += __shfl_xor(px, 32);
            py += __shfl_xor(py, 16); py += __shfl_xor(py, 32);
            pz += __shfl_xor(pz, 16); pz += __shfl_xor(pz, 32);
            int node = __shfl(myR, lo);
            float val = (q == 0) ? ps : (q == 1) ? px : (q == 2) ? py : pz;
            atomicAdd(out + (size_t)node * 64 + m * 4 + q, val);
        }

        rc = nrc;
    }
}

// -------------------- gate: s' = silu(s), v' = v * sigmoid(s)
__global__ void gate_kernel(float4* __restrict__ feat) {
    int i = blockIdx.x * blockDim.x + threadIdx.x;   // (n*16 + w)
    if (i >= N_NODES * 16) return;
    float4 f = feat[i];
    float g = 1.f / (1.f + __expf(-f.x));
    feat[i] = make_float4(f.x * g, f.y * g, f.z * g, f.w * g);
}

// -------------------- readout
__global__ void readout_kernel(const float4* __restrict__ feat,
                               const int* __restrict__ batch_idx,
                               const float* __restrict__ w_out,
                               float* __restrict__ energy) {
    __shared__ float bins[N_GRAPHS];
    int t = threadIdx.x;
    if (t < N_GRAPHS) bins[t] = 0.f;
    __syncthreads();
    int n = blockIdx.x * blockDim.x + t;
    if (n < N_NODES) {
        const float4* f = feat + (size_t)n * 16;
        float acc = 0.f;
#pragma unroll
        for (int w = 0; w < 16; ++w) acc += f[w].x * w_out[w];
        atomicAdd(&bins[batch_idx[n]], acc * INV_LIN_OUT);
    }
    __syncthreads();
    if (t < N_GRAPHS) atomicAdd(&energy[t], bins[t]);
}

extern "C" void kernel_launch(void* const* d_in, const int* in_sizes, int n_in,
                              void* d_out, int out_size, void* d_ws, size_t ws_size,
                              hipStream_t stream) {
    const float* x         = (const float*)d_in[0];
    const int*   row       = (const int*)d_in[1];
    const int*   col       = (const int*)d_in[2];
    const int*   batch_idx = (const int*)d_in[3];
    const float* w_in0     = (const float*)d_in[4];
    const float* w_in1     = (const float*)d_in[5];
    const float* tp_w      = (const float*)d_in[6];   // [3][5][16][16][16]
    const float* w_out0    = (const float*)d_in[7];
    float* energy = (float*)d_out;

    // workspace layout (28.1 MB total)
    float* bufA = (float*)d_ws;                            // [N][64] f32
    float* bufB = bufA + (size_t)N_NODES * 64;             // [N][64] f32
    short* wbf  = (short*)(bufB + (size_t)N_NODES * 64);   // [3][5][8][64][8] bf16
    int* sortedRC = (int*)(wbf + 3 * 20480);               // [E] packed (row | col<<16)
    // transient sort scratch aliased into bufB (dead until layer-0 memset)
    int* counts  = (int*)bufB;
    int* cursor  = counts + N_NODES;
    int* partial = cursor + N_NODES;
    int* partOff = partial + 256;

    // build destination-sorted edge list (row is static across layers)
    hipMemsetAsync(counts, 0, N_NODES * sizeof(int), stream);
    hist_kernel<<<(N_EDGES + 255) / 256, 256, 0, stream>>>(row, counts);
    scan_part_kernel<<<NPART, 256, 0, stream>>>(counts, partial);
    scan_partials_kernel<<<1, 256, 0, stream>>>(partial, partOff);
    scan_final_kernel<<<NPART, 256, 0, stream>>>(counts, partOff, cursor);
    scatter_kernel<<<(N_EDGES + 255) / 256, 256, 0, stream>>>(row, col, cursor, sortedRC);

    swizzle_w_kernel<<<(3 * 20480 + 255) / 256, 256, 0, stream>>>(tp_w, wbf);
    proj_kernel<<<(N_NODES + 255) / 256, 256, 0, stream>>>(x, w_in0, w_in1, (float4*)bufA);

    float* fin = bufA;
    float* fout = bufB;
    for (int l = 0; l < 3; ++l) {
        hipMemsetAsync(fout, 0, (size_t)N_NODES * 64 * sizeof(float), stream);
        edge_tp_kernel<<<1024, 256, 0, stream>>>(
            (const float4*)fin, fout, sortedRC, wbf + (size_t)l * 20480);
        gate_kernel<<<(N_NODES * 16 + 255) / 256, 256, 0, stream>>>((float4*)fout);
        float* t = fin; fin = fout; fout = t;
    }

    hipMemsetAsync(energy, 0, N_GRAPHS * sizeof(float), stream);
    readout_kernel<<<(N_NODES + 255) / 256, 256, 0, stream>>>(
        (const float4*)fin, batch_idx, w_out0, energy);
}